// Round 1
// baseline (524.508 us; speedup 1.0000x reference)
//
#include <hip/hip_runtime.h>

#define B_ 8
#define T_ 4096
#define W_ 1024
#define H_ 8
#define BW_ 128
#define M_ 128          // timesteps per chunk
#define NC_ 32          // chunks per sequence (T_/M_)
#define XS 136          // LDS row stride (halves): 272B rows
#define NG_ 32          // 4-step groups per chunk
#define NS_ 8           // 16-step segments per chunk

typedef __attribute__((ext_vector_type(8))) short bf16x8;
typedef __attribute__((ext_vector_type(4))) float f32x4;

__device__ __forceinline__ float bf2f(unsigned short u) {
    return __uint_as_float(((unsigned)u) << 16);
}
__device__ __forceinline__ unsigned short f2bf(float f) {
    unsigned u = __float_as_uint(f);
    u += 0x7fffu + ((u >> 16) & 1u);       // round-nearest-even
    return (unsigned short)(u >> 16);
}
__device__ __forceinline__ unsigned short f2h_bits(float f) {
    union { _Float16 h; unsigned short u; } cv;
    cv.h = (_Float16)f;
    return cv.u;
}
__device__ __forceinline__ float h2f(unsigned short u) {
    union { _Float16 h; unsigned short u; } cv;
    cv.u = u;
    return (float)cv.h;
}
__device__ __forceinline__ float sigmoidf_(float z) {
    return 1.0f / (1.0f + __expf(-z));
}

// ---------------- prep: fp32 weights -> transposed bf16 [h][j][i] in ws; cj = -8*softplus(a_param)
// also zeroes the chain array (value+flag carry handoff) for this launch
__global__ __launch_bounds__(256) void prep_kernel(
    const float* __restrict__ w_in, const float* __restrict__ w_a,
    const float* __restrict__ a_param,
    unsigned short* __restrict__ wt_in, unsigned short* __restrict__ wt_a,
    float* __restrict__ cj, unsigned long long* __restrict__ chain)
{
    int gid = blockIdx.x * 256 + threadIdx.x;     // 0..32767
    if (gid < W_) {
        float ap = a_param[gid];
        cj[gid] = -8.0f * log1pf(__expf(ap));
    }
    // zero chain: 64*32*128 = 262144 entries, 8 per thread
    #pragma unroll
    for (int k = 0; k < 8; ++k) chain[(size_t)gid * 8 + k] = 0ull;

    int mat  = gid >> 14;          // 0: w_in, 1: w_a
    int rem  = gid & 16383;
    int hh   = rem >> 11;          // head
    int r2   = rem & 2047;
    int seg  = r2 >> 7;            // i-segment (8 elems)
    int jrow = r2 & 127;           // output row j (low bits -> coalesced fp32 reads)
    const float* src = (mat ? w_a : w_in) + hh * BW_ * BW_;
    unsigned short* dst = (mat ? wt_a : wt_in) + hh * BW_ * BW_;
    unsigned short tmp[8] __attribute__((aligned(16)));
    #pragma unroll
    for (int k = 0; k < 8; ++k) tmp[k] = f2bf(src[(seg * 8 + k) * BW_ + jrow]);
    *(uint4*)(dst + jrow * BW_ + seg * 8) = *(const uint4*)tmp;
}

// ---------------- fused main: gates (MFMA) + elementwise + chunk scan + inter-block
// chained carry (decoupled serial chain: packed {flag,value} 8B agent-scope atomics).
// bid = c*64 + s so a chunk's predecessor (bid-64) is always dispatched earlier.
__global__ __launch_bounds__(1024, 4) void rg_fused(
    const float* __restrict__ x,
    const unsigned short* __restrict__ wt_in,
    const unsigned short* __restrict__ wt_a,
    const float* __restrict__ b_in,
    const float* __restrict__ b_a,
    const float* __restrict__ cj,
    unsigned long long* __restrict__ chain,
    float* __restrict__ y)
{
    __shared__ alignas(16) unsigned short Xs[M_ * XS];    // 34816 B: x bf16, overwritten with nx
    __shared__ alignas(16) unsigned short Ah[M_ * XS];    // 34816 B: a fp16 (replay)
    __shared__ alignas(16) unsigned short Wsh[BW_ * XS];  // 34816 B: Wt bf16
    __shared__ float2 G[NG_ * BW_];                       // 32768 B: 4-step (A,E) aggregates
    __shared__ float2 S2[NS_ * BW_];                      //  8192 B: 16-step (A,E) aggregates
    __shared__ float qin[NS_ * BW_];                      //  4096 B: segment carry-ins
    __shared__ float cj_s[BW_], ba_s[BW_], bi_s[BW_];

    const int tid = threadIdx.x;
    const int bid = blockIdx.x;
    const int c = bid >> 6;          // chunk index 0..31 (dispatch order: all seqs of chunk c before c+1)
    const int s = bid & 63;          // sequence 0..63
    const int b = s >> 3;
    const int h = s & 7;
    const int t0 = c * M_;

    const float* xg = x + ((size_t)b * T_ + t0) * W_ + h * BW_;
    const unsigned short* wag = wt_a + h * BW_ * BW_;
    const unsigned short* wig = wt_in + h * BW_ * BW_;

    // stage X tile (fp32 -> bf16)
    #pragma unroll
    for (int r = 0; r < 4; ++r) {
        int u = tid + r * 1024;        // 0..4095
        int t = u >> 5, sg = u & 31;   // 4 floats per sg
        const float4 v = *(const float4*)(xg + (size_t)t * W_ + sg * 4);
        ushort4 hv;
        hv.x = f2bf(v.x); hv.y = f2bf(v.y); hv.z = f2bf(v.z); hv.w = f2bf(v.w);
        *(ushort4*)&Xs[t * XS + sg * 4] = hv;
    }
    // stage Wt_a tile; prefetch Wt_in to registers (both already bf16)
    uint4 wreg[2];
    #pragma unroll
    for (int r = 0; r < 2; ++r) {
        int u = tid + r * 1024;
        int t = u >> 4, seg = u & 15;
        *(uint4*)&Wsh[t * XS + seg * 8] = *(const uint4*)(wag + t * BW_ + seg * 8);
        wreg[r] = *(const uint4*)(wig + t * BW_ + seg * 8);
    }
    if (tid < BW_) {
        cj_s[tid] = cj[h * BW_ + tid];
        ba_s[tid] = b_a[h * BW_ + tid];
        bi_s[tid] = b_in[h * BW_ + tid];
    }
    __syncthreads();

    const int wave = tid >> 6;
    const int lane = tid & 63;
    const int q  = lane >> 4;
    const int cl = lane & 15;
    const int mw = wave >> 1;       // 0..7: 16-row group
    const int nw = wave & 1;        // 0..1: 64-col half

    f32x4 zero4 = {0.0f, 0.0f, 0.0f, 0.0f};
    f32x4 acc_a[4], acc_x[4];
    #pragma unroll
    for (int nt = 0; nt < 4; ++nt) { acc_a[nt] = zero4; acc_x[nt] = zero4; }

    // gate_a pass; keep A-fragments in registers for reuse in gate_x pass
    bf16x8 af[4];
    #pragma unroll
    for (int kk = 0; kk < 4; ++kk) {
        af[kk] = *(const bf16x8*)&Xs[(mw * 16 + cl) * XS + kk * 32 + q * 8];
        #pragma unroll
        for (int nt = 0; nt < 4; ++nt) {
            bf16x8 bf = *(const bf16x8*)&Wsh[(nw * 64 + nt * 16 + cl) * XS + kk * 32 + q * 8];
            acc_a[nt] = __builtin_amdgcn_mfma_f32_16x16x32_bf16(af[kk], bf, acc_a[nt], 0, 0, 0);
        }
    }
    __syncthreads();
    #pragma unroll
    for (int r = 0; r < 2; ++r) {
        int u = tid + r * 1024;
        int t = u >> 4, seg = u & 15;
        *(uint4*)&Wsh[t * XS + seg * 8] = wreg[r];
    }
    __syncthreads();
    // gate_x pass
    #pragma unroll
    for (int kk = 0; kk < 4; ++kk) {
        #pragma unroll
        for (int nt = 0; nt < 4; ++nt) {
            bf16x8 bf = *(const bf16x8*)&Wsh[(nw * 64 + nt * 16 + cl) * XS + kk * 32 + q * 8];
            acc_x[nt] = __builtin_amdgcn_mfma_f32_16x16x32_bf16(af[kk], bf, acc_x[nt], 0, 0, 0);
        }
    }

    // elementwise: a = exp(cj*sigmoid), nx = x*gx*sqrt(1-a^2); 4-step aggregates in registers
    #pragma unroll
    for (int nt = 0; nt < 4; ++nt) {
        int j = nw * 64 + nt * 16 + cl;
        float cjv = cj_s[j], bav = ba_s[j], biv = bi_s[j];
        float A4 = 1.0f, E4 = 0.0f;
        #pragma unroll
        for (int r = 0; r < 4; ++r) {
            int tl = mw * 16 + q * 4 + r;                       // C/D layout: row = q*4 + r
            float la = cjv * sigmoidf_(acc_a[nt][r] + bav);     // log_a <= 0
            float a  = __expf(la);
            float gx = sigmoidf_(acc_x[nt][r] + biv);
            float xv = bf2f(Xs[tl * XS + j]);
            float mult = sqrtf(fmaxf(1.0f - a * a, 0.0f));
            if (t0 + tl == 0) { a = 0.0f; mult = 1.0f; }        // reset at global t=0
            float nxv = xv * gx * mult;
            unsigned short nxb = f2bf(nxv);
            float nxr = bf2f(nxb);
            E4 = fmaf(a, E4, nxr);
            A4 *= a;
            Ah[tl * XS + j] = f2h_bits(a);
            Xs[tl * XS + j] = nxb;       // in-place: sole reader is this thread (xv above)
        }
        G[(mw * 4 + q) * BW_ + j] = make_float2(A4, E4);
    }
    __syncthreads();

    // level 2: 16-step segment aggregates (all 1024 threads)
    {
        int sg = tid >> 7, jq = tid & 127;
        float A = 1.0f, E = 0.0f;
        #pragma unroll
        for (int i = 0; i < 4; ++i) {
            float2 g = G[(sg * 4 + i) * BW_ + jq];
            E = fmaf(g.x, E, g.y);
            A *= g.x;
        }
        S2[sg * BW_ + jq] = make_float2(A, E);
    }
    __syncthreads();

    // chunk aggregate + inter-block chained carry + segment carry-ins
    if (tid < BW_) {
        float At = 1.0f, Et = 0.0f;
        #pragma unroll
        for (int s8 = 0; s8 < NS_; ++s8) {
            float2 v = S2[s8 * BW_ + tid];
            Et = fmaf(v.x, Et, v.y);
            At *= v.x;
        }
        size_t base = ((size_t)s * NC_ + c) * BW_ + tid;
        float hin = 0.0f;
        if (c > 0) {
            unsigned long long v;
            do {
                v = __hip_atomic_load(&chain[base - BW_], __ATOMIC_ACQUIRE, __HIP_MEMORY_SCOPE_AGENT);
            } while ((v >> 32) == 0ull);
            hin = __uint_as_float((unsigned)v);
        }
        if (c < NC_ - 1) {
            // publish inclusive carry for successor ASAP (identical arithmetic to old carry_scan)
            float Hout = fmaf(At, hin, Et);
            unsigned long long pv = (1ull << 32) | (unsigned long long)__float_as_uint(Hout);
            __hip_atomic_store(&chain[base], pv, __ATOMIC_RELEASE, __HIP_MEMORY_SCOPE_AGENT);
        }
        float hh = hin;
        #pragma unroll
        for (int s8 = 0; s8 < NS_; ++s8) {
            qin[s8 * BW_ + tid] = hh;
            float2 v = S2[s8 * BW_ + tid];
            hh = fmaf(v.x, hh, v.y);
        }
    }
    __syncthreads();

    // replay: apply carries, write y
    const int jq = tid & 127;
    const int qq = tid >> 7;
    float hcur = qin[qq * BW_ + jq];
    float* yg = y + ((size_t)b * T_ + t0) * W_ + h * BW_ + jq;
    #pragma unroll 4
    for (int i = 0; i < 16; ++i) {
        int t = qq * 16 + i;
        float a   = h2f(Ah[t * XS + jq]);
        float nxv = bf2f(Xs[t * XS + jq]);
        hcur = fmaf(a, hcur, nxv);
        yg[(size_t)t * W_] = hcur;     // coalesced across jq lanes
    }
}

extern "C" void kernel_launch(void* const* d_in, const int* in_sizes, int n_in,
                              void* d_out, int out_size, void* d_ws, size_t ws_size,
                              hipStream_t stream)
{
    const float* x     = (const float*)d_in[0];
    const float* w_in  = (const float*)d_in[1];
    const float* b_in  = (const float*)d_in[2];
    const float* w_a   = (const float*)d_in[3];
    const float* b_a   = (const float*)d_in[4];
    const float* a_par = (const float*)d_in[5];
    float* y = (float*)d_out;

    char* ws = (char*)d_ws;
    unsigned short* wt_in = (unsigned short*)(ws);
    unsigned short* wt_a  = (unsigned short*)(ws + 262144);
    float* cj             = (float*)(ws + 524288);
    unsigned long long* chain = (unsigned long long*)(ws + 528384);  // 8B-aligned, 2 MB
    if (ws_size < 2625536) return;

    prep_kernel<<<dim3(128), dim3(256), 0, stream>>>(w_in, w_a, a_par, wt_in, wt_a, cj, chain);
    rg_fused<<<dim3(2048), dim3(1024), 0, stream>>>(
        x, wt_in, wt_a, b_in, b_a, cj, chain, y);
}

// Round 2
// 372.954 us; speedup vs baseline: 1.4064x; 1.4064x over previous
//
#include <hip/hip_runtime.h>

#define B_ 8
#define T_ 4096
#define W_ 1024
#define H_ 8
#define BW_ 128
#define M_ 128          // timesteps per chunk
#define NC_ 32          // chunks per sequence (T_/M_)
#define XS 136          // LDS row stride (halves): 272B rows
#define NG_ 32          // 4-step groups per chunk
#define NS_ 8           // 16-step segments per chunk

typedef __attribute__((ext_vector_type(8))) short bf16x8;
typedef __attribute__((ext_vector_type(4))) float f32x4;

__device__ __forceinline__ float bf2f(unsigned short u) {
    return __uint_as_float(((unsigned)u) << 16);
}
__device__ __forceinline__ unsigned short f2bf(float f) {
    unsigned u = __float_as_uint(f);
    u += 0x7fffu + ((u >> 16) & 1u);       // round-nearest-even
    return (unsigned short)(u >> 16);
}
__device__ __forceinline__ unsigned short f2h_bits(float f) {
    union { _Float16 h; unsigned short u; } cv;
    cv.h = (_Float16)f;
    return cv.u;
}
__device__ __forceinline__ float h2f(unsigned short u) {
    union { _Float16 h; unsigned short u; } cv;
    cv.u = u;
    return (float)cv.h;
}
__device__ __forceinline__ float sigmoidf_(float z) {
    return 1.0f / (1.0f + __expf(-z));
}

// ---------------- prep: fp32 weights -> transposed bf16 [h][j][i] in ws; cj = -8*softplus(a_param)
__global__ __launch_bounds__(256) void prep_kernel(
    const float* __restrict__ w_in, const float* __restrict__ w_a,
    const float* __restrict__ a_param,
    unsigned short* __restrict__ wt_in, unsigned short* __restrict__ wt_a,
    float* __restrict__ cj)
{
    int gid = blockIdx.x * 256 + threadIdx.x;     // 0..32767
    if (gid < W_) {
        float ap = a_param[gid];
        cj[gid] = -8.0f * log1pf(__expf(ap));
    }
    int mat  = gid >> 14;          // 0: w_in, 1: w_a
    int rem  = gid & 16383;
    int hh   = rem >> 11;          // head
    int r2   = rem & 2047;
    int seg  = r2 >> 7;            // i-segment (8 elems)
    int jrow = r2 & 127;           // output row j (low bits -> coalesced fp32 reads)
    const float* src = (mat ? w_a : w_in) + hh * BW_ * BW_;
    unsigned short* dst = (mat ? wt_a : wt_in) + hh * BW_ * BW_;
    unsigned short tmp[8] __attribute__((aligned(16)));
    #pragma unroll
    for (int k = 0; k < 8; ++k) tmp[k] = f2bf(src[(seg * 8 + k) * BW_ + jrow]);
    *(uint4*)(dst + jrow * BW_ + seg * 8) = *(const uint4*)tmp;
}

// ---------------- K2: sequential scan over chunk aggregates -> exclusive carries
__global__ __launch_bounds__(256) void carry_scan(
    const float* __restrict__ aggA, const float* __restrict__ aggE, float* __restrict__ carry)
{
    int g = blockIdx.x * 256 + threadIdx.x;   // 0..8191
    int s = g >> 7, j = g & 127;
    float hh = 0.0f;
    for (int c = 0; c < NC_; ++c) {
        size_t idx = ((size_t)s * NC_ + c) * BW_ + j;
        carry[idx] = hh;                       // state BEFORE chunk c
        hh = fmaf(aggA[idx], hh, aggE[idx]);
    }
}

// ---------------- K1: gates (MFMA) + elementwise, computed ONCE.
// Writes packed (a:fp16 hi | nx:fp16 lo) u32 per element + per-chunk aggregates.
__global__ __launch_bounds__(1024, 4) void rg_gates(
    const float* __restrict__ x,
    const unsigned short* __restrict__ wt_in,
    const unsigned short* __restrict__ wt_a,
    const float* __restrict__ b_in,
    const float* __restrict__ b_a,
    const float* __restrict__ cj,
    float* __restrict__ aggA, float* __restrict__ aggE,
    unsigned int* __restrict__ packed)
{
    __shared__ alignas(16) unsigned short Xs[M_ * XS];    // x bf16, overwritten with nx fp16
    __shared__ alignas(16) unsigned short Ah[M_ * XS];    // a fp16
    __shared__ alignas(16) unsigned short Wsh[BW_ * XS];  // Wt bf16
    __shared__ float2 G[NG_ * BW_];                       // 4-step (A,E) aggregates
    __shared__ float2 S2[NS_ * BW_];                      // 16-step (A,E) aggregates
    __shared__ float cj_s[BW_], ba_s[BW_], bi_s[BW_];

    const int tid = threadIdx.x;
    const int bid = blockIdx.x;
    const int c = bid & (NC_ - 1);
    const int s = bid >> 5;
    const int b = s >> 3;
    const int h = s & 7;
    const int t0 = c * M_;

    const float* xg = x + ((size_t)b * T_ + t0) * W_ + h * BW_;
    const unsigned short* wag = wt_a + h * BW_ * BW_;
    const unsigned short* wig = wt_in + h * BW_ * BW_;

    // stage X tile (fp32 -> bf16)
    #pragma unroll
    for (int r = 0; r < 4; ++r) {
        int u = tid + r * 1024;        // 0..4095
        int t = u >> 5, sg = u & 31;   // 4 floats per sg
        const float4 v = *(const float4*)(xg + (size_t)t * W_ + sg * 4);
        ushort4 hv;
        hv.x = f2bf(v.x); hv.y = f2bf(v.y); hv.z = f2bf(v.z); hv.w = f2bf(v.w);
        *(ushort4*)&Xs[t * XS + sg * 4] = hv;
    }
    // stage Wt_a tile; prefetch Wt_in to registers (both already bf16)
    uint4 wreg[2];
    #pragma unroll
    for (int r = 0; r < 2; ++r) {
        int u = tid + r * 1024;
        int t = u >> 4, seg = u & 15;
        *(uint4*)&Wsh[t * XS + seg * 8] = *(const uint4*)(wag + t * BW_ + seg * 8);
        wreg[r] = *(const uint4*)(wig + t * BW_ + seg * 8);
    }
    if (tid < BW_) {
        cj_s[tid] = cj[h * BW_ + tid];
        ba_s[tid] = b_a[h * BW_ + tid];
        bi_s[tid] = b_in[h * BW_ + tid];
    }
    __syncthreads();

    const int wave = tid >> 6;
    const int lane = tid & 63;
    const int q  = lane >> 4;
    const int cl = lane & 15;
    const int mw = wave >> 1;       // 0..7: 16-row group
    const int nw = wave & 1;        // 0..1: 64-col half

    f32x4 zero4 = {0.0f, 0.0f, 0.0f, 0.0f};
    f32x4 acc_a[4], acc_x[4];
    #pragma unroll
    for (int nt = 0; nt < 4; ++nt) { acc_a[nt] = zero4; acc_x[nt] = zero4; }

    // gate_a pass; keep A-fragments in registers for reuse in gate_x pass
    bf16x8 af[4];
    #pragma unroll
    for (int kk = 0; kk < 4; ++kk) {
        af[kk] = *(const bf16x8*)&Xs[(mw * 16 + cl) * XS + kk * 32 + q * 8];
        #pragma unroll
        for (int nt = 0; nt < 4; ++nt) {
            bf16x8 bf = *(const bf16x8*)&Wsh[(nw * 64 + nt * 16 + cl) * XS + kk * 32 + q * 8];
            acc_a[nt] = __builtin_amdgcn_mfma_f32_16x16x32_bf16(af[kk], bf, acc_a[nt], 0, 0, 0);
        }
    }
    __syncthreads();
    #pragma unroll
    for (int r = 0; r < 2; ++r) {
        int u = tid + r * 1024;
        int t = u >> 4, seg = u & 15;
        *(uint4*)&Wsh[t * XS + seg * 8] = wreg[r];
    }
    __syncthreads();
    // gate_x pass
    #pragma unroll
    for (int kk = 0; kk < 4; ++kk) {
        #pragma unroll
        for (int nt = 0; nt < 4; ++nt) {
            bf16x8 bf = *(const bf16x8*)&Wsh[(nw * 64 + nt * 16 + cl) * XS + kk * 32 + q * 8];
            acc_x[nt] = __builtin_amdgcn_mfma_f32_16x16x32_bf16(af[kk], bf, acc_x[nt], 0, 0, 0);
        }
    }

    // elementwise: a = exp(cj*sigmoid), nx = x*gx*sqrt(1-a^2); 4-step aggregates in registers
    #pragma unroll
    for (int nt = 0; nt < 4; ++nt) {
        int j = nw * 64 + nt * 16 + cl;
        float cjv = cj_s[j], bav = ba_s[j], biv = bi_s[j];
        float A4 = 1.0f, E4 = 0.0f;
        #pragma unroll
        for (int r = 0; r < 4; ++r) {
            int tl = mw * 16 + q * 4 + r;                       // C/D layout: row = q*4 + r
            float la = cjv * sigmoidf_(acc_a[nt][r] + bav);     // log_a <= 0
            float a  = __expf(la);
            float gx = sigmoidf_(acc_x[nt][r] + biv);
            float xv = bf2f(Xs[tl * XS + j]);
            float mult = sqrtf(fmaxf(1.0f - a * a, 0.0f));
            if (t0 + tl == 0) { a = 0.0f; mult = 1.0f; }        // reset at global t=0
            float nxv = xv * gx * mult;
            unsigned short nxb = f2h_bits(nxv);
            float nxr = h2f(nxb);
            E4 = fmaf(a, E4, nxr);
            A4 *= a;
            Ah[tl * XS + j] = f2h_bits(a);
            Xs[tl * XS + j] = nxb;       // in-place: sole reader is this thread (xv above)
        }
        G[(mw * 4 + q) * BW_ + j] = make_float2(A4, E4);
    }
    __syncthreads();

    // packed writeout: (a_fp16 << 16) | nx_fp16, coalesced rows
    {
        unsigned int* pg = packed + ((size_t)b * T_ + t0) * W_ + h * BW_;
        const int jj = tid & 127;
        const int rr = tid >> 7;       // 8 rows per sweep
        #pragma unroll
        for (int i = 0; i < 16; ++i) {
            int t = i * 8 + rr;
            unsigned int pv = ((unsigned int)Ah[t * XS + jj] << 16) | (unsigned int)Xs[t * XS + jj];
            pg[(size_t)t * W_ + jj] = pv;
        }
    }

    // level 2: 16-step segment aggregates (all 1024 threads)
    {
        int sg = tid >> 7, jq = tid & 127;
        float A = 1.0f, E = 0.0f;
        #pragma unroll
        for (int i = 0; i < 4; ++i) {
            float2 g = G[(sg * 4 + i) * BW_ + jq];
            E = fmaf(g.x, E, g.y);
            A *= g.x;
        }
        S2[sg * BW_ + jq] = make_float2(A, E);
    }
    __syncthreads();

    // chunk aggregate write
    if (tid < BW_) {
        float At = 1.0f, Et = 0.0f;
        #pragma unroll
        for (int s8 = 0; s8 < NS_; ++s8) {
            float2 v = S2[s8 * BW_ + tid];
            Et = fmaf(v.x, Et, v.y);
            At *= v.x;
        }
        size_t idx = ((size_t)s * NC_ + c) * BW_ + tid;
        aggA[idx] = At;
        aggE[idx] = Et;
    }
}

// ---------------- K3: streaming scan + replay from packed (a,nx); no MFMA, no transcendentals
__global__ __launch_bounds__(1024, 4) void rg_scan(
    const unsigned int* __restrict__ packed,
    const float* __restrict__ carry,
    float* __restrict__ y)
{
    __shared__ float2 S2[NS_ * BW_];
    __shared__ float qin[NS_ * BW_];

    const int tid = threadIdx.x;
    const int bid = blockIdx.x;
    const int c = bid & (NC_ - 1);
    const int s = bid >> 5;
    const int b = s >> 3;
    const int h = s & 7;
    const int t0 = c * M_;

    const unsigned int* pg = packed + ((size_t)b * T_ + t0) * W_ + h * BW_;
    const int j  = tid & 127;
    const int qq = tid >> 7;        // 16-step segment

    unsigned int v[16];
    #pragma unroll
    for (int i = 0; i < 16; ++i)
        v[i] = pg[(size_t)(qq * 16 + i) * W_ + j];

    float A = 1.0f, E = 0.0f;
    #pragma unroll
    for (int i = 0; i < 16; ++i) {
        float a  = h2f((unsigned short)(v[i] >> 16));
        float nx = h2f((unsigned short)(v[i] & 0xffffu));
        E = fmaf(a, E, nx);
        A *= a;
    }
    S2[qq * BW_ + j] = make_float2(A, E);
    __syncthreads();

    if (tid < BW_) {
        float hh = carry[((size_t)s * NC_ + c) * BW_ + tid];
        #pragma unroll
        for (int s8 = 0; s8 < NS_; ++s8) {
            qin[s8 * BW_ + tid] = hh;
            float2 w = S2[s8 * BW_ + tid];
            hh = fmaf(w.x, hh, w.y);
        }
    }
    __syncthreads();

    float hcur = qin[qq * BW_ + j];
    float* yg = y + ((size_t)b * T_ + t0) * W_ + h * BW_ + j;
    #pragma unroll
    for (int i = 0; i < 16; ++i) {
        float a  = h2f((unsigned short)(v[i] >> 16));
        float nx = h2f((unsigned short)(v[i] & 0xffffu));
        hcur = fmaf(a, hcur, nx);
        yg[(size_t)(qq * 16 + i) * W_] = hcur;     // coalesced across j lanes
    }
}

// ---------------- fallback (round-0 verified): gates recomputed in both passes
template<bool FINAL>
__global__ __launch_bounds__(1024, 4) void rg_main(
    const float* __restrict__ x,
    const unsigned short* __restrict__ wt_in,
    const unsigned short* __restrict__ wt_a,
    const float* __restrict__ b_in,
    const float* __restrict__ b_a,
    const float* __restrict__ cj,
    float* __restrict__ aggA, float* __restrict__ aggE,
    const float* __restrict__ carry,
    float* __restrict__ y)
{
    __shared__ alignas(16) unsigned short Xs[M_ * XS];
    __shared__ alignas(16) unsigned short Ah[M_ * XS];
    __shared__ alignas(16) unsigned short Wsh[BW_ * XS];
    __shared__ float2 G[NG_ * BW_];
    __shared__ float2 S2[NS_ * BW_];
    __shared__ float qin[NS_ * BW_];
    __shared__ float cj_s[BW_], ba_s[BW_], bi_s[BW_];

    const int tid = threadIdx.x;
    const int bid = blockIdx.x;
    const int c = bid & (NC_ - 1);
    const int s = bid >> 5;
    const int b = s >> 3;
    const int h = s & 7;
    const int t0 = c * M_;

    const float* xg = x + ((size_t)b * T_ + t0) * W_ + h * BW_;
    const unsigned short* wag = wt_a + h * BW_ * BW_;
    const unsigned short* wig = wt_in + h * BW_ * BW_;

    #pragma unroll
    for (int r = 0; r < 4; ++r) {
        int u = tid + r * 1024;
        int t = u >> 5, sg = u & 31;
        const float4 v = *(const float4*)(xg + (size_t)t * W_ + sg * 4);
        ushort4 hv;
        hv.x = f2bf(v.x); hv.y = f2bf(v.y); hv.z = f2bf(v.z); hv.w = f2bf(v.w);
        *(ushort4*)&Xs[t * XS + sg * 4] = hv;
    }
    uint4 wreg[2];
    #pragma unroll
    for (int r = 0; r < 2; ++r) {
        int u = tid + r * 1024;
        int t = u >> 4, seg = u & 15;
        *(uint4*)&Wsh[t * XS + seg * 8] = *(const uint4*)(wag + t * BW_ + seg * 8);
        wreg[r] = *(const uint4*)(wig + t * BW_ + seg * 8);
    }
    if (tid < BW_) {
        cj_s[tid] = cj[h * BW_ + tid];
        ba_s[tid] = b_a[h * BW_ + tid];
        bi_s[tid] = b_in[h * BW_ + tid];
    }
    __syncthreads();

    const int wave = tid >> 6;
    const int lane = tid & 63;
    const int q  = lane >> 4;
    const int cl = lane & 15;
    const int mw = wave >> 1;
    const int nw = wave & 1;

    f32x4 zero4 = {0.0f, 0.0f, 0.0f, 0.0f};
    f32x4 acc_a[4], acc_x[4];
    #pragma unroll
    for (int nt = 0; nt < 4; ++nt) { acc_a[nt] = zero4; acc_x[nt] = zero4; }

    bf16x8 af[4];
    #pragma unroll
    for (int kk = 0; kk < 4; ++kk) {
        af[kk] = *(const bf16x8*)&Xs[(mw * 16 + cl) * XS + kk * 32 + q * 8];
        #pragma unroll
        for (int nt = 0; nt < 4; ++nt) {
            bf16x8 bf = *(const bf16x8*)&Wsh[(nw * 64 + nt * 16 + cl) * XS + kk * 32 + q * 8];
            acc_a[nt] = __builtin_amdgcn_mfma_f32_16x16x32_bf16(af[kk], bf, acc_a[nt], 0, 0, 0);
        }
    }
    __syncthreads();
    #pragma unroll
    for (int r = 0; r < 2; ++r) {
        int u = tid + r * 1024;
        int t = u >> 4, seg = u & 15;
        *(uint4*)&Wsh[t * XS + seg * 8] = wreg[r];
    }
    __syncthreads();
    #pragma unroll
    for (int kk = 0; kk < 4; ++kk) {
        #pragma unroll
        for (int nt = 0; nt < 4; ++nt) {
            bf16x8 bf = *(const bf16x8*)&Wsh[(nw * 64 + nt * 16 + cl) * XS + kk * 32 + q * 8];
            acc_x[nt] = __builtin_amdgcn_mfma_f32_16x16x32_bf16(af[kk], bf, acc_x[nt], 0, 0, 0);
        }
    }

    #pragma unroll
    for (int nt = 0; nt < 4; ++nt) {
        int j = nw * 64 + nt * 16 + cl;
        float cjv = cj_s[j], bav = ba_s[j], biv = bi_s[j];
        float A4 = 1.0f, E4 = 0.0f;
        #pragma unroll
        for (int r = 0; r < 4; ++r) {
            int tl = mw * 16 + q * 4 + r;
            float la = cjv * sigmoidf_(acc_a[nt][r] + bav);
            float a  = __expf(la);
            float gx = sigmoidf_(acc_x[nt][r] + biv);
            float xv = bf2f(Xs[tl * XS + j]);
            float mult = sqrtf(fmaxf(1.0f - a * a, 0.0f));
            if (t0 + tl == 0) { a = 0.0f; mult = 1.0f; }
            float nxv = xv * gx * mult;
            unsigned short nxb = f2bf(nxv);
            float nxr = bf2f(nxb);
            E4 = fmaf(a, E4, nxr);
            A4 *= a;
            if (FINAL) {
                Ah[tl * XS + j] = f2h_bits(a);
                Xs[tl * XS + j] = nxb;
            }
        }
        G[(mw * 4 + q) * BW_ + j] = make_float2(A4, E4);
    }
    __syncthreads();

    {
        int sg = tid >> 7, jq = tid & 127;
        float A = 1.0f, E = 0.0f;
        #pragma unroll
        for (int i = 0; i < 4; ++i) {
            float2 g = G[(sg * 4 + i) * BW_ + jq];
            E = fmaf(g.x, E, g.y);
            A *= g.x;
        }
        S2[sg * BW_ + jq] = make_float2(A, E);
    }
    __syncthreads();

    if (!FINAL) {
        if (tid < BW_) {
            float At = 1.0f, Et = 0.0f;
            #pragma unroll
            for (int s8 = 0; s8 < NS_; ++s8) {
                float2 v = S2[s8 * BW_ + tid];
                Et = fmaf(v.x, Et, v.y);
                At *= v.x;
            }
            size_t idx = ((size_t)s * NC_ + c) * BW_ + tid;
            aggA[idx] = At;
            aggE[idx] = Et;
        }
    } else {
        if (tid < BW_) {
            float hh = carry[((size_t)s * NC_ + c) * BW_ + tid];
            #pragma unroll
            for (int s8 = 0; s8 < NS_; ++s8) {
                qin[s8 * BW_ + tid] = hh;
                float2 v = S2[s8 * BW_ + tid];
                hh = fmaf(v.x, hh, v.y);
            }
        }
        __syncthreads();
        const int jq = tid & 127;
        const int qq = tid >> 7;
        float hcur = qin[qq * BW_ + jq];
        float* yg = y + ((size_t)b * T_ + t0) * W_ + h * BW_ + jq;
        #pragma unroll 4
        for (int i = 0; i < 16; ++i) {
            int t = qq * 16 + i;
            float a   = h2f(Ah[t * XS + jq]);
            float nxv = bf2f(Xs[t * XS + jq]);
            hcur = fmaf(a, hcur, nxv);
            yg[(size_t)t * W_] = hcur;
        }
    }
}

extern "C" void kernel_launch(void* const* d_in, const int* in_sizes, int n_in,
                              void* d_out, int out_size, void* d_ws, size_t ws_size,
                              hipStream_t stream)
{
    const float* x     = (const float*)d_in[0];
    const float* w_in  = (const float*)d_in[1];
    const float* b_in  = (const float*)d_in[2];
    const float* w_a   = (const float*)d_in[3];
    const float* b_a   = (const float*)d_in[4];
    const float* a_par = (const float*)d_in[5];
    float* y = (float*)d_out;

    char* ws = (char*)d_ws;
    unsigned short* wt_in = (unsigned short*)(ws);
    unsigned short* wt_a  = (unsigned short*)(ws + 262144);
    float* cj    = (float*)(ws + 524288);
    float* aggA  = (float*)(ws + 528384);
    float* aggE  = (float*)(ws + 1576960);
    float* carry = (float*)(ws + 2625536);
    unsigned int* packed = (unsigned int*)(ws + 3674112);

    const size_t OLD_WS = 3674112ull;
    const size_t NEW_WS = OLD_WS + (size_t)B_ * T_ * W_ * 4ull;   // +128 MB packed

    if (ws_size >= NEW_WS) {
        prep_kernel<<<dim3(128), dim3(256), 0, stream>>>(w_in, w_a, a_par, wt_in, wt_a, cj);
        rg_gates<<<dim3(2048), dim3(1024), 0, stream>>>(
            x, wt_in, wt_a, b_in, b_a, cj, aggA, aggE, packed);
        carry_scan<<<dim3(32), dim3(256), 0, stream>>>(aggA, aggE, carry);
        rg_scan<<<dim3(2048), dim3(1024), 0, stream>>>(packed, carry, y);
    } else if (ws_size >= OLD_WS) {
        prep_kernel<<<dim3(128), dim3(256), 0, stream>>>(w_in, w_a, a_par, wt_in, wt_a, cj);
        rg_main<false><<<dim3(2048), dim3(1024), 0, stream>>>(
            x, wt_in, wt_a, b_in, b_a, cj, aggA, aggE, (const float*)nullptr, (float*)nullptr);
        carry_scan<<<dim3(32), dim3(256), 0, stream>>>(aggA, aggE, carry);
        rg_main<true><<<dim3(2048), dim3(1024), 0, stream>>>(
            x, wt_in, wt_a, b_in, b_a, cj, aggA, aggE, carry, y);
    }
}